// Round 1
// baseline (640.478 us; speedup 1.0000x reference)
//
#include <hip/hip_runtime.h>

// DGMC: B=4, NS=NT=512, D_IN=128, C1=64, R=C2=32, E=32768, STEPS=10
// Key optimization: pairwise MLP update decomposes as
//   upd[s,t] = mb2 + sum_j relu(P_s[s,j] - P_t[t,j]) * mw2[j]
// with P_s = (o_s @ mw1) + mb1, P_t = o_t @ mw1  (3 VALU ops per (pair,j)).

constexpr int kB = 4;
constexpr int kNS = 512;
constexpr int kNT = 512;
constexpr int kDin = 128;
constexpr int kC1 = 64;
constexpr int kR = 32;
constexpr int kC2 = 32;
constexpr int kE = 32768;
constexpr int kSteps = 10;
constexpr int kN = kB * kNS;  // 2048 nodes per side

// ---------------- CSR build ----------------
__global__ void k_hist(const int* __restrict__ ei_s, const int* __restrict__ ei_t,
                       int* __restrict__ deg) {
  int g = blockIdx.y;
  const int* dst = (g ? ei_t : ei_s) + kE;
  int e = blockIdx.x * 256 + threadIdx.x;
  atomicAdd(&deg[g * kN + dst[e]], 1);
}

__global__ void k_scan(const int* __restrict__ deg, int* __restrict__ off,
                       int* __restrict__ cur) {
  int g = blockIdx.x;
  const int* d = deg + g * kN;
  int* o = off + g * (kN + 1);
  int* c = cur + g * kN;
  __shared__ int sums[256];
  int tid = threadIdx.x;
  int loc[8];
  int s = 0;
#pragma unroll
  for (int i = 0; i < 8; ++i) { loc[i] = d[tid * 8 + i]; s += loc[i]; }
  sums[tid] = s;
  __syncthreads();
  for (int st = 1; st < 256; st <<= 1) {
    int v = (tid >= st) ? sums[tid - st] : 0;
    __syncthreads();
    sums[tid] += v;
    __syncthreads();
  }
  int base = (tid > 0) ? sums[tid - 1] : 0;
#pragma unroll
  for (int i = 0; i < 8; ++i) {
    int idx = tid * 8 + i;
    o[idx] = base;
    c[idx] = base;
    base += loc[i];
  }
  if (tid == 255) o[kN] = base;
}

__global__ void k_scatter(const int* __restrict__ ei_s, const int* __restrict__ ei_t,
                          const float* __restrict__ ea_s, const float* __restrict__ ea_t,
                          int* __restrict__ cur, int* __restrict__ srcs,
                          float* __restrict__ eaw) {
  int g = blockIdx.y;
  const int* ei = g ? ei_t : ei_s;
  const float* ea = g ? ea_t : ea_s;
  int e = blockIdx.x * 256 + threadIdx.x;
  int d = ei[kE + e];
  int srcv = ei[e];
  int pos = atomicAdd(&cur[g * kN + d], 1);
  srcs[g * kE + pos] = srcv;
  eaw[g * kE + pos] = ea[e];
}

// ---------------- psi with W1: h = relu((x + agg) @ W1) ----------------
__global__ __launch_bounds__(128) void k_psi1(
    const float* __restrict__ x_s, const float* __restrict__ x_t,
    const int* __restrict__ srcs, const float* __restrict__ eaw,
    const int* __restrict__ off, const float* __restrict__ W1, float* __restrict__ h) {
  int g = blockIdx.y;
  const float* x = g ? x_t : x_s;
  const int* sr = srcs + g * kE;
  const float* ew = eaw + g * kE;
  const int* o = off + g * (kN + 1);
  float* ho = h + (size_t)g * kN * kC1;
  int n = blockIdx.x, f = threadIdx.x;
  __shared__ float y[kDin];
  int beg = o[n], end = o[n + 1];
  float m = 0.f;
  for (int idx = beg; idx < end; ++idx)
    m += x[(size_t)sr[idx] * kDin + f] * ew[idx];
  y[f] = x[(size_t)n * kDin + f] + m;
  __syncthreads();
  if (f < kC1) {
    float acc = 0.f;
#pragma unroll 16
    for (int k = 0; k < kDin; ++k) acc += y[k] * W1[k * kC1 + f];
    ho[(size_t)n * kC1 + f] = fmaxf(acc, 0.f);
  }
}

// ---------------- S_hat0 = h_s @ h_t^T (per batch) ----------------
__global__ __launch_bounds__(256) void k_shat0(const float* __restrict__ h,
                                               float* __restrict__ Shat) {
  int b = blockIdx.z, s0 = blockIdx.y * 64, t0 = blockIdx.x * 64;
  const float* hs = h + (size_t)(b * kNS + s0) * kC1;
  const float* ht = h + (size_t)kN * kC1 + (size_t)(b * kNT + t0) * kC1;
  __shared__ float As[64 * 68];  // pad 68 floats: (row+cc)%8 bank-quad spread
  __shared__ float Bs[64 * 68];
  int tid = threadIdx.x;
#pragma unroll
  for (int k2 = 0; k2 < 4; ++k2) {
    int idx = tid + k2 * 256;  // 1024 float4
    int row = idx >> 4, c4 = idx & 15;
    float4 va = *(const float4*)(hs + (size_t)row * kC1 + c4 * 4);
    *(float4*)&As[row * 68 + c4 * 4] = va;
    float4 vb = *(const float4*)(ht + (size_t)row * kC1 + c4 * 4);
    *(float4*)&Bs[row * 68 + c4 * 4] = vb;
  }
  __syncthreads();
  int ts = tid >> 4, tt = tid & 15;
  float acc[4][4] = {};
#pragma unroll
  for (int cc = 0; cc < 16; ++cc) {
    float4 a[4], bt[4];
#pragma unroll
    for (int i = 0; i < 4; ++i) a[i] = *(const float4*)&As[(ts * 4 + i) * 68 + cc * 4];
#pragma unroll
    for (int k = 0; k < 4; ++k) bt[k] = *(const float4*)&Bs[(tt + 16 * k) * 68 + cc * 4];
#pragma unroll
    for (int i = 0; i < 4; ++i)
#pragma unroll
      for (int k = 0; k < 4; ++k)
        acc[i][k] += a[i].x * bt[k].x + a[i].y * bt[k].y + a[i].z * bt[k].z + a[i].w * bt[k].w;
  }
#pragma unroll
  for (int i = 0; i < 4; ++i) {
    int s = s0 + ts * 4 + i;
    float* row = Shat + (size_t)(b * kNS + s) * kNT;
#pragma unroll
    for (int k = 0; k < 4; ++k) row[t0 + tt + 16 * k] = acc[i][k];
  }
}

// ---------------- row softmax -> dst ----------------
__global__ __launch_bounds__(256) void k_softmax(const float* __restrict__ Shat,
                                                 float* __restrict__ dst) {
  int row = blockIdx.x, tid = threadIdx.x;
  const float* p = Shat + (size_t)row * kNT;
  float v0 = p[tid], v1 = p[tid + 256];
  __shared__ float sm[4];
  float mx = fmaxf(v0, v1);
#pragma unroll
  for (int o = 32; o; o >>= 1) mx = fmaxf(mx, __shfl_down(mx, o, 64));
  if ((tid & 63) == 0) sm[tid >> 6] = mx;
  __syncthreads();
  mx = fmaxf(fmaxf(sm[0], sm[1]), fmaxf(sm[2], sm[3]));
  float e0 = __expf(v0 - mx), e1 = __expf(v1 - mx);
  float s = e0 + e1;
  __syncthreads();
#pragma unroll
  for (int o = 32; o; o >>= 1) s += __shfl_down(s, o, 64);
  if ((tid & 63) == 0) sm[tid >> 6] = s;
  __syncthreads();
  float rinv = 1.f / (sm[0] + sm[1] + sm[2] + sm[3]);
  float* d = dst + (size_t)row * kNT;
  d[tid] = e0 * rinv;
  d[tid + 256] = e1 * rinv;
}

// ---------------- row stats (max, 1/sumexp) + zero rt ----------------
__global__ __launch_bounds__(256) void k_rowstats(const float* __restrict__ Shat,
                                                  float* __restrict__ rowm,
                                                  float* __restrict__ rowl,
                                                  float* __restrict__ rt) {
  int row = blockIdx.x, tid = threadIdx.x;
  const float* p = Shat + (size_t)row * kNT;
  float v0 = p[tid], v1 = p[tid + 256];
  __shared__ float sm[4];
  float mx = fmaxf(v0, v1);
#pragma unroll
  for (int o = 32; o; o >>= 1) mx = fmaxf(mx, __shfl_down(mx, o, 64));
  if ((tid & 63) == 0) sm[tid >> 6] = mx;
  __syncthreads();
  mx = fmaxf(fmaxf(sm[0], sm[1]), fmaxf(sm[2], sm[3]));
  float s = __expf(v0 - mx) + __expf(v1 - mx);
  __syncthreads();
#pragma unroll
  for (int o = 32; o; o >>= 1) s += __shfl_down(s, o, 64);
  if ((tid & 63) == 0) sm[tid >> 6] = s;
  __syncthreads();
  if (tid == 0) {
    rowm[row] = mx;
    rowl[row] = 1.f / (sm[0] + sm[1] + sm[2] + sm[3]);
  }
  if (tid < kR) rt[(size_t)row * kR + tid] = 0.f;  // zero rt for k_rt's atomics
}

// ---------------- r_t = S^T @ r_i (partial over 64-s chunk, atomic finish) ----
__global__ __launch_bounds__(256) void k_rt(const float* __restrict__ Shat,
                                            const float* __restrict__ rowm,
                                            const float* __restrict__ rowl,
                                            const float* __restrict__ ri,
                                            float* __restrict__ rt) {
  int b = blockIdx.z, s0 = blockIdx.y * 64, t0 = blockIdx.x * 64;
  __shared__ float Wt[64 * 64];
  __shared__ float rch[64 * 32];
  int tid = threadIdx.x;
#pragma unroll
  for (int k2 = 0; k2 < 4; ++k2) {
    int idx = tid + k2 * 256;
    int row = idx >> 4, c4 = idx & 15;
    int grow = b * kNS + s0 + row;
    float4 v = *(const float4*)(Shat + (size_t)grow * kNT + t0 + c4 * 4);
    float m = rowm[grow], l = rowl[grow];
    float4 wv;
    wv.x = __expf(v.x - m) * l;
    wv.y = __expf(v.y - m) * l;
    wv.z = __expf(v.z - m) * l;
    wv.w = __expf(v.w - m) * l;
    *(float4*)&Wt[row * 64 + c4 * 4] = wv;
  }
#pragma unroll
  for (int k2 = 0; k2 < 2; ++k2) {
    int idx = tid + k2 * 256;
    int row = idx >> 3, c4 = idx & 7;
    float4 v = *(const float4*)(ri + (size_t)(b * kNS + s0 + row) * kR + c4 * 4);
    *(float4*)&rch[row * 32 + c4 * 4] = v;
  }
  __syncthreads();
  int t_l = tid & 63, jg = tid >> 6;  // jg uniform per wave -> rch reads broadcast
  float acc[8] = {};
  for (int s = 0; s < 64; ++s) {
    float wv = Wt[s * 64 + t_l];
    float4 ra = *(const float4*)&rch[s * 32 + jg * 8];
    float4 rb = *(const float4*)&rch[s * 32 + jg * 8 + 4];
    acc[0] += wv * ra.x; acc[1] += wv * ra.y; acc[2] += wv * ra.z; acc[3] += wv * ra.w;
    acc[4] += wv * rb.x; acc[5] += wv * rb.y; acc[6] += wv * rb.z; acc[7] += wv * rb.w;
  }
  float* dst = rt + (size_t)(b * kNT + t0 + t_l) * kR + jg * 8;
#pragma unroll
  for (int q = 0; q < 8; ++q) atomicAdd(&dst[q], acc[q]);
}

// ---------------- psi with W2, fused P = o @ mw1 (+mb1 on s-side) ----------
__global__ __launch_bounds__(64) void k_psi2(
    const float* __restrict__ rin_s, const float* __restrict__ rin_t,
    const int* __restrict__ srcs, const float* __restrict__ eaw,
    const int* __restrict__ off, const float* __restrict__ W2,
    const float* __restrict__ mw1, const float* __restrict__ mb1,
    float* __restrict__ Ps, float* __restrict__ Pt) {
  int side = blockIdx.y;
  const float* vin = side ? rin_t : rin_s;
  const int* sr = srcs + side * kE;
  const float* ew = eaw + side * kE;
  const int* o = off + side * (kN + 1);
  float* Pout = side ? Pt : Ps;
  int n = blockIdx.x, tid = threadIdx.x;
  int f = tid & 31, hh = tid >> 5;
  __shared__ float v[32], ov[32];
  int beg = o[n], end = o[n + 1];
  float m = 0.f;
  for (int idx = beg + hh; idx < end; idx += 2)
    m += vin[(size_t)sr[idx] * kR + f] * ew[idx];
  m += __shfl_down(m, 32, 64);
  if (tid < 32) v[f] = vin[(size_t)n * kR + f] + m;
  __syncthreads();
  if (tid < 32) {
    float acc = 0.f;
#pragma unroll
    for (int k = 0; k < 32; ++k) acc += v[k] * W2[k * kC2 + f];
    ov[f] = fmaxf(acc, 0.f);
  }
  __syncthreads();
  if (tid < 32) {
    float p = side ? 0.f : mb1[f];
#pragma unroll
    for (int k = 0; k < 32; ++k) p += ov[k] * mw1[k * kC2 + f];
    Pout[(size_t)n * kC2 + f] = p;
  }
}

// ---------------- pairwise update: Shat += mb2 + sum_j relu(Ps-Pt)*mw2 -----
__global__ __launch_bounds__(256) void k_update(float* __restrict__ Shat,
                                                const float* __restrict__ Ps,
                                                const float* __restrict__ Pt,
                                                const float* __restrict__ mw2,
                                                const float* __restrict__ mb2) {
  int b = blockIdx.z, s0 = blockIdx.y * 64, t0 = blockIdx.x * 64;
  __shared__ float ps[64 * 36];  // pad 36 floats (9 f4): bank-quad spread
  __shared__ float qt[64 * 36];
  int tid = threadIdx.x;
  const float4* srcS = (const float4*)(Ps + (size_t)(b * kNS + s0) * kC2);
  const float4* srcT = (const float4*)(Pt + (size_t)(b * kNT + t0) * kC2);
#pragma unroll
  for (int k2 = 0; k2 < 2; ++k2) {
    int i = tid + k2 * 256;  // 512 float4
    int row = i >> 3, col = i & 7;
    float4 a = srcS[i];
    *(float4*)&ps[row * 36 + col * 4] = a;
    float4 c = srcT[i];
    *(float4*)&qt[row * 36 + col * 4] = c;
  }
  float w2[32];
#pragma unroll
  for (int j = 0; j < 32; ++j) w2[j] = mw2[j];  // uniform -> SGPR loads
  float bias = mb2[0];
  __syncthreads();
  int ts = tid >> 4, tt = tid & 15;
  float acc[4][4] = {};
#pragma unroll
  for (int jc = 0; jc < 8; ++jc) {
    float4 a[4], bt[4];
#pragma unroll
    for (int i = 0; i < 4; ++i) a[i] = *(const float4*)&ps[(ts * 4 + i) * 36 + jc * 4];
#pragma unroll
    for (int k = 0; k < 4; ++k) bt[k] = *(const float4*)&qt[(tt + 16 * k) * 36 + jc * 4];
#pragma unroll
    for (int i = 0; i < 4; ++i)
#pragma unroll
      for (int k = 0; k < 4; ++k) {
        acc[i][k] += fmaxf(a[i].x - bt[k].x, 0.f) * w2[jc * 4 + 0];
        acc[i][k] += fmaxf(a[i].y - bt[k].y, 0.f) * w2[jc * 4 + 1];
        acc[i][k] += fmaxf(a[i].z - bt[k].z, 0.f) * w2[jc * 4 + 2];
        acc[i][k] += fmaxf(a[i].w - bt[k].w, 0.f) * w2[jc * 4 + 3];
      }
  }
#pragma unroll
  for (int i = 0; i < 4; ++i) {
    int s = s0 + ts * 4 + i;
    float* row = Shat + (size_t)(b * kNS + s) * kNT;
#pragma unroll
    for (int k = 0; k < 4; ++k) {
      int t = t0 + tt + 16 * k;
      row[t] += acc[i][k] + bias;
    }
  }
}

extern "C" void kernel_launch(void* const* d_in, const int* in_sizes, int n_in,
                              void* d_out, int out_size, void* d_ws, size_t ws_size,
                              hipStream_t stream) {
  (void)in_sizes; (void)n_in; (void)out_size; (void)ws_size;
  const float* x_s = (const float*)d_in[0];
  const int* ei_s = (const int*)d_in[1];
  const float* ea_s = (const float*)d_in[2];
  const float* x_t = (const float*)d_in[4];
  const int* ei_t = (const int*)d_in[5];
  const float* ea_t = (const float*)d_in[6];
  const float* W1 = (const float*)d_in[8];
  const float* W2 = (const float*)d_in[9];
  const float* mw1 = (const float*)d_in[10];
  const float* mb1 = (const float*)d_in[11];
  const float* mw2 = (const float*)d_in[12];
  const float* mb2 = (const float*)d_in[13];
  const float* r = (const float*)d_in[14];
  float* out = (float*)d_out;

  char* w = (char*)d_ws;
  auto alloc = [&](size_t bytes) -> void* {
    void* p = (void*)w;
    w += (bytes + 255) & ~(size_t)255;
    return p;
  };
  int* deg = (int*)alloc((size_t)2 * kN * 4);
  int* off = (int*)alloc((size_t)2 * (kN + 1) * 4);
  int* cur = (int*)alloc((size_t)2 * kN * 4);
  int* srcs = (int*)alloc((size_t)2 * kE * 4);
  float* eaw = (float*)alloc((size_t)2 * kE * 4);
  float* h = (float*)alloc((size_t)2 * kN * kC1 * 4);
  float* Shat = (float*)alloc((size_t)kB * kNS * kNT * 4);
  float* rowm = (float*)alloc((size_t)kN * 4);
  float* rowl = (float*)alloc((size_t)kN * 4);
  float* rt = (float*)alloc((size_t)kN * kR * 4);
  float* Ps = (float*)alloc((size_t)kN * kC2 * 4);
  float* Pt = (float*)alloc((size_t)kN * kC2 * 4);

  hipMemsetAsync(deg, 0, (size_t)2 * kN * 4, stream);
  k_hist<<<dim3(kE / 256, 2), 256, 0, stream>>>(ei_s, ei_t, deg);
  k_scan<<<2, 256, 0, stream>>>(deg, off, cur);
  k_scatter<<<dim3(kE / 256, 2), 256, 0, stream>>>(ei_s, ei_t, ea_s, ea_t, cur, srcs, eaw);
  k_psi1<<<dim3(kN, 2), 128, 0, stream>>>(x_s, x_t, srcs, eaw, off, W1, h);
  k_shat0<<<dim3(8, 8, kB), 256, 0, stream>>>(h, Shat);
  k_softmax<<<kN, 256, 0, stream>>>(Shat, out);  // S_0
  for (int i = 0; i < kSteps; ++i) {
    const float* ri = r + (size_t)i * kB * kNS * kR;
    k_rowstats<<<kN, 256, 0, stream>>>(Shat, rowm, rowl, rt);
    k_rt<<<dim3(8, 8, kB), 256, 0, stream>>>(Shat, rowm, rowl, ri, rt);
    k_psi2<<<dim3(kN, 2), 64, 0, stream>>>(ri, rt, srcs, eaw, off, W2, mw1, mb1, Ps, Pt);
    k_update<<<dim3(8, 8, kB), 256, 0, stream>>>(Shat, Ps, Pt, mw2, mb2);
  }
  k_softmax<<<kN, 256, 0, stream>>>(Shat, out + (size_t)kB * kNS * kNT);  // S_L
}